// Round 10
// baseline (351.689 us; speedup 1.0000x reference)
//
#include <hip/hip_runtime.h>

// ---------------------------------------------------------------------------
// RCSM engine, MI355X/gfx950.  FP32 in/out.  Round 18:
//  * r17 post-mortem: k_down fix good (-21 us).  Non-pass2 pool ~190 us.
//  * Budget audit: r12's "one block per tensor" k_absum streams 512 KB of
//    W_down/W_up through a SINGLE CU (~25 GB/s latency-limited) = ~20 us
//    with 221 CUs idle.  REVERT to r8 absum: memset + 8 blocks/tensor +
//    atomicAdd (64 KB/block, ~5 us total).
//  * k_up: Rf MFMA A-reads were scattered (lane stride 256 B, 16 B reqs —
//    same pattern fixed in k_down).  Stage Rf tile in LDS coalesced via a
//    UNION with cs (17.4 KB inside cs's 33.8 KB; frags->regs behind a
//    barrier before cs overwrites).  LDS size/occupancy unchanged.
//  * k_pass2 / k_down / k_build byte-identical to r17 (frozen).
// ---------------------------------------------------------------------------

#define DR   128
#define DM   1024
#define NTOK 16384
#define NOPS 32
#define COEF (1e-5f / 32.f)

typedef __attribute__((ext_vector_type(8))) short bfrag;   // 8 x bf16 bits
typedef __attribute__((ext_vector_type(4))) float f32x4;

__device__ __forceinline__ ushort f2b_bits(float f) {
  union { float f; uint i; } c; c.f = f;
  uint x = c.i;
  return (ushort)((x + 0x7fffu + ((x >> 16) & 1u)) >> 16);   // RNE
}
__device__ __forceinline__ float qeff(float w, float s) {
  float q = rintf(w / s);
  q = fminf(1.f, fmaxf(-1.f, q));
  return q * s;
}
__device__ __forceinline__ float waveRed(float v) {
#pragma unroll
  for (int m = 32; m > 0; m >>= 1) v += __shfl_xor(v, m, 64);
  return v;
}

// ---------------- ws layout (bytes; total ~5.9 MB) -------------------------
#define OFF_SUMS    0
#define OFF_OPSSC   256
#define OFF_WDE     512
#define OFF_WUE     (OFF_WDE + 262144)
#define OFF_WRT     (OFF_WUE + 262144)
#define OFF_OPSB    (OFF_WRT + 16384)
#define OFF_WMIXA   (OFF_OPSB + 1048576)
#define OFF_WWVB    (OFF_WMIXA + 32768)
#define OFF_MRS     (OFF_WWVB + 32768)
#define OFF_MWS     (OFF_MRS + 8192)
#define OFF_SB      (OFF_MWS + 8192)
#define OFF_SLOTS   (OFF_SB + 8192)
#define OFF_WWG     (OFF_SLOTS + 8192)
#define OFF_GAMMA   (OFF_WWG + 512)
#define OFF_BETA    (OFF_GAMMA + 512)
#define OFF_WSC     (OFF_BETA + 512)
#define OFF_RF      (OFF_WSC + 256)
#define WS_TOTAL    (OFF_RF + 4194304)

// ----------------- abs-sum reductions: 8 blocks/tensor + atomics -----------
__global__ __launch_bounds__(256) void k_absum_all(
    const float* __restrict__ W_down, const float* __restrict__ W_router,
    const float* __restrict__ W_up, const float* __restrict__ ops,
    float* __restrict__ sums) {
  __shared__ float ws4[4];
  const int y = blockIdx.y;
  const float* src; int n; float* dst;
  if (y == 0)      { src = W_down;   n = 131072; dst = &sums[0]; }
  else if (y == 1) { src = W_router; n = 4096;   dst = &sums[1]; }
  else if (y == 2) { src = W_up;     n = 131072; dst = &sums[2]; }
  else { src = ops + (size_t)(y - 3) * 16384; n = 16384; dst = &sums[y]; }
  float s = 0.f;
  for (int i = blockIdx.x * 256 + threadIdx.x; i < n; i += 8 * 256)
    s += fabsf(src[i]);
  s = waveRed(s);
  int lane = threadIdx.x & 63, wv = threadIdx.x >> 6;
  if (lane == 0) ws4[wv] = s;
  __syncthreads();
  if (threadIdx.x == 0) atomicAdd(dst, ws4[0] + ws4[1] + ws4[2] + ws4[3]);
}

// --------------------------- weight build ----------------------------------
__global__ __launch_bounds__(256) void k_build(
    const float* __restrict__ W_down, const float* __restrict__ W_up,
    const float* __restrict__ W_router, const float* __restrict__ ops,
    const float* __restrict__ W_read, const float* __restrict__ W_wk,
    const float* __restrict__ W_wg, const float* __restrict__ W_wv,
    const float* __restrict__ W_mix, const float* __restrict__ slots,
    const float* __restrict__ gamma, const float* __restrict__ beta,
    const float* __restrict__ wscale, int has_wsc, const float* __restrict__ sums,
    ushort* __restrict__ WdE, ushort* __restrict__ WuE, float* __restrict__ WrT,
    ushort* __restrict__ opsB, float* __restrict__ opsScale,
    ushort* __restrict__ WmixA, ushort* __restrict__ WwvB,
    float* __restrict__ Mrs, float* __restrict__ Mws, float* __restrict__ SBw,
    float* __restrict__ slotsF, float* __restrict__ WwgF,
    float* __restrict__ gammaF, float* __restrict__ betaF, float* __restrict__ wscF) {
  int id = blockIdx.x * 256 + threadIdx.x;
  const float s_wd = fmaxf(sums[0] * (1.f / 131072.f), 1e-5f);
  const float s_wr = fmaxf(sums[1] * (1.f / 4096.f), 1e-5f);
  const float s_wu = fmaxf(sums[2] * (1.f / 131072.f), 1e-5f);

  if (id < 131072) { WdE[id] = f2b_bits(qeff(W_down[id], s_wd)); return; }
  id -= 131072;
  if (id < 131072) { WuE[id] = f2b_bits(qeff(W_up[id], s_wu)); return; }
  id -= 131072;
  if (id < 4096) {
    int d = id >> 5, n = id & 31;
    WrT[id] = qeff(W_router[n * DR + d], s_wr);
    return;
  }
  id -= 4096;
  if (id < 524288) {
    int n = id >> 14;
    float s = fmaxf(sums[3 + n] * (1.f / 16384.f), 1e-5f);
    float q = rintf(ops[id] / s);
    q = fminf(1.f, fmaxf(-1.f, q));
    opsB[id] = f2b_bits(q);
    return;
  }
  id -= 524288;
  if (id < 32) { opsScale[id] = fmaxf(sums[3 + id] * (1.f / 16384.f), 1e-5f); return; }
  id -= 32;
  if (id < 16384) {
    int r = id >> 7, o = id & 127;
    WmixA[id] = f2b_bits(W_mix[r * 256 + o]);
    return;
  }
  id -= 16384;
  if (id < 16384) { WwvB[id] = f2b_bits(W_wv[id]); return; }
  id -= 16384;
  if (id < 2048) {
    int d = id >> 4, j = id & 15;
    float a = 0.f;
#pragma unroll 8
    for (int o = 0; o < DR; ++o) a += W_read[o * DR + d] * slots[j * DR + o];
    Mrs[id] = a;
    return;
  }
  id -= 2048;
  if (id < 2048) {
    int d = id >> 4, j = id & 15;
    float a = 0.f;
#pragma unroll 8
    for (int o = 0; o < DR; ++o) a += W_wk[o * DR + d] * slots[j * DR + o];
    Mws[id] = a;
    return;
  }
  id -= 2048;
  if (id < 2048) {
    int j = id >> 7, r = id & 127;
    float a = 0.f;
#pragma unroll 8
    for (int o = 0; o < DR; ++o) a += slots[j * DR + o] * W_mix[r * 256 + 128 + o];
    SBw[id] = a;
    return;
  }
  id -= 2048;
  if (id < 2048) { slotsF[id] = slots[id]; return; }
  id -= 2048;
  if (id < 128) { WwgF[id] = W_wg[id]; return; }
  id -= 128;
  if (id < 128) { gammaF[id] = gamma[id]; return; }
  id -= 128;
  if (id < 128) { betaF[id] = beta[id]; return; }
  id -= 128;
  if (id == 0) { wscF[0] = has_wsc ? wscale[0] : 0.01f; }
}

// ------ down projection: LDS-staged coalesced MFMA GEMM --------------------
// 256 blocks x 512 threads; 64 tokens/block; K chunked 8 x 128.
__global__ __launch_bounds__(512) void k_down(const float* __restrict__ hidden,
                                              const ushort* __restrict__ WdE,
                                              float* __restrict__ X) {
  __shared__ ushort stg[64][136];      // 17.4 KB staging (bf16, padded)

  const int tid = threadIdx.x;
  const int w = tid >> 6, lane = tid & 63;
  const int quad = lane >> 4, mrow = lane & 15;
  const int t0 = blockIdx.x * 64;

  f32x4 dacc[4];
#pragma unroll
  for (int m = 0; m < 4; ++m) dacc[m] = (f32x4){0.f, 0.f, 0.f, 0.f};

  for (int kc = 0; kc < 8; ++kc) {
    // coalesced load+convert of the 64x128 chunk (consecutive tid -> cols)
    for (int i = tid; i < 2048; i += 512) {
      int t = i >> 5, c = (i & 31) * 4;
      float4 v = *(const float4*)(hidden + (size_t)(t0 + t) * DM + kc * 128 + c);
      stg[t][c] = f2b_bits(v.x); stg[t][c + 1] = f2b_bits(v.y);
      stg[t][c + 2] = f2b_bits(v.z); stg[t][c + 3] = f2b_bits(v.w);
    }
    __syncthreads();
#pragma unroll
    for (int kt = 0; kt < 4; ++kt) {
      bfrag b = *(const bfrag*)(WdE + (size_t)(w * 16 + mrow) * DM + kc * 128 + kt * 32 + quad * 8);
#pragma unroll
      for (int m = 0; m < 4; ++m) {
        bfrag a = *(const bfrag*)&stg[m * 16 + mrow][kt * 32 + quad * 8];
        dacc[m] = __builtin_amdgcn_mfma_f32_16x16x32_bf16(a, b, dacc[m], 0, 0, 0);
      }
    }
    __syncthreads();
  }
#pragma unroll
  for (int m = 0; m < 4; ++m)
#pragma unroll
    for (int r = 0; r < 4; ++r)
      X[(size_t)(t0 + m * 16 + quad * 4 + r) * DR + w * 16 + mrow] = dacc[m][r];
}

// -------------------------- fused pass kernel ------------------------------
// 256 blocks x 512 threads; 64 tokens/block.  Small weight tables staged in
// LDS.  emit==0: X updated in-place.  emit==1: write-signal fused, RF written.
__global__ __launch_bounds__(512) void k_pass2(
    float* __restrict__ X, ushort* __restrict__ RF, int emit,
    const float* __restrict__ WrT, const ushort* __restrict__ opsB,
    const float* __restrict__ opsScale, const ushort* __restrict__ WmixA,
    const float* __restrict__ Mrs, const float* __restrict__ SBw,
    const float* __restrict__ gammaF, const float* __restrict__ betaF,
    const ushort* __restrict__ WwvB, const float* __restrict__ Mws,
    const float* __restrict__ slotsF, const float* __restrict__ WwgF,
    const float* __restrict__ wscF) {
  __shared__ float  xsf[64][132];      // 33.8 KB (pad: col access 2-way, free)
  __shared__ ushort xsb[64][136];      // 17 KB
  __shared__ float  lg[64][33];        // 8.4 KB
  __shared__ float  coefT[32][64];     // 8 KB
  __shared__ float  attn[64][17];      // 4.3 KB
  __shared__ float  at2[64][17];       // 4.3 KB
  __shared__ float  WrTs[4096];        // 16 KB  (staged weight tables)
  __shared__ float  Mrss[2048];        // 8 KB
  __shared__ float  Mwss[2048];        // 8 KB
  __shared__ float  SBws[2048];        // 8 KB
  __shared__ float  slotss[2048];      // 8 KB
  __shared__ int    seli[64][2];
  __shared__ float  selw[64][2];
  __shared__ float  gp[64];
  __shared__ float  partS[8][4][4];    // cross-wave LN partials
  __shared__ float  partQ[8][4][4];

  const int tid = threadIdx.x;
  const int w = tid >> 6, lane = tid & 63;
  const int quad = lane >> 4, mrow = lane & 15;
  const int t0 = blockIdx.x * 64;

  // ---- P0: stage weight tables + X tile -> LDS
  {
    float4* d;
    const float4* s;
    d = (float4*)WrTs; s = (const float4*)WrT;
    for (int i = tid; i < 1024; i += 512) d[i] = s[i];
    ((float4*)Mrss)[tid]   = ((const float4*)Mrs)[tid];
    ((float4*)Mwss)[tid]   = ((const float4*)Mws)[tid];
    ((float4*)SBws)[tid]   = ((const float4*)SBw)[tid];
    ((float4*)slotss)[tid] = ((const float4*)slotsF)[tid];
  }
  for (int i = tid; i < 2048; i += 512) {
    float4 v = *(const float4*)(X + (size_t)t0 * DR + i * 4);
    int t = i >> 5, c = (i & 31) * 4;
    xsf[t][c] = v.x; xsf[t][c + 1] = v.y; xsf[t][c + 2] = v.z; xsf[t][c + 3] = v.w;
    xsb[t][c] = f2b_bits(v.x); xsb[t][c + 1] = f2b_bits(v.y);
    xsb[t][c + 2] = f2b_bits(v.z); xsb[t][c + 3] = f2b_bits(v.w);
  }
  __syncthreads();

  // ---- P1: router logits + read-slot scores (all LDS operands)
  for (int p = tid; p < 2048; p += 512) {
    int t = p >> 5, n = p & 31;
    const float4* xr = (const float4*)&xsf[t][0];
    float a = 0.f;
#pragma unroll 8
    for (int d4 = 0; d4 < 32; ++d4) {
      float4 x = xr[d4];
      a += x.x * WrTs[(d4 * 4 + 0) * 32 + n];
      a += x.y * WrTs[(d4 * 4 + 1) * 32 + n];
      a += x.z * WrTs[(d4 * 4 + 2) * 32 + n];
      a += x.w * WrTs[(d4 * 4 + 3) * 32 + n];
    }
    lg[t][n] = a;
  }
  for (int p = tid; p < 1024; p += 512) {
    int t = p >> 4, j = p & 15;
    const float4* xr = (const float4*)&xsf[t][0];
    float a = 0.f;
#pragma unroll 8
    for (int d4 = 0; d4 < 32; ++d4) {
      float4 x = xr[d4];
      a += x.x * Mrss[(d4 * 4 + 0) * 16 + j];
      a += x.y * Mrss[(d4 * 4 + 1) * 16 + j];
      a += x.z * Mrss[(d4 * 4 + 2) * 16 + j];
      a += x.w * Mrss[(d4 * 4 + 3) * 16 + j];
    }
    attn[t][j] = a * 0.088388347648318447f;
  }
  __syncthreads();

  // topk (wave 0) || attn softmax (wave 1): parallel serial sections
  if (tid < 64) {
    float v0 = -1e30f; int i0 = 0;
#pragma unroll
    for (int n = 0; n < 32; ++n) { float v = lg[tid][n]; if (v > v0) { v0 = v; i0 = n; } }
    float v1 = -1e30f; int i1 = 0;
#pragma unroll
    for (int n = 0; n < 32; ++n)
      if (n != i0) { float v = lg[tid][n]; if (v > v1) { v1 = v; i1 = n; } }
    float e = expf(v1 - v0);
    float w0 = 1.f / (1.f + e);
    seli[tid][0] = i0; seli[tid][1] = i1;
    selw[tid][0] = w0; selw[tid][1] = e * w0;
  } else if (tid < 128) {
    const int t = tid - 64;
    float m = -1e30f;
#pragma unroll
    for (int j = 0; j < 16; ++j) m = fmaxf(m, attn[t][j]);
    float s = 0.f;
#pragma unroll
    for (int j = 0; j < 16; ++j) { float ee = expf(attn[t][j] - m); attn[t][j] = ee; s += ee; }
    float inv = 1.f / s;
#pragma unroll
    for (int j = 0; j < 16; ++j) attn[t][j] *= inv;
  }
  __syncthreads();

  for (int p = tid; p < 2048; p += 512) {
    int n = p >> 6, t = p & 63;
    float cf = COEF;
    if (n == seli[t][0]) cf += selw[t][0];
    if (n == seli[t][1]) cf += selw[t][1];
    coefT[n][t] = cf * opsScale[n];
  }
  __syncthreads();

  // ---- P2: 32-op MFMA GEMM.  Wave w owns cols w*16..+15, all 4 m-tiles.
  bfrag a[4][4];
#pragma unroll
  for (int m = 0; m < 4; ++m)
#pragma unroll
    for (int kt = 0; kt < 4; ++kt)
      a[m][kt] = *(const bfrag*)&xsb[m * 16 + mrow][kt * 32 + quad * 8];

  const ushort* Bp = opsB + (size_t)(w * 16 + mrow) * DR + quad * 8;
  bfrag bc[4], bn[4];
#pragma unroll
  for (int kt = 0; kt < 4; ++kt) bc[kt] = *(const bfrag*)(Bp + kt * 32);

  f32x4 out[4];
#pragma unroll
  for (int m = 0; m < 4; ++m) out[m] = (f32x4){0.f, 0.f, 0.f, 0.f};

  for (int n = 0; n < NOPS; ++n) {
    if (n + 1 < NOPS) {
      const ushort* Bn = Bp + (size_t)(n + 1) * (DR * DR);
#pragma unroll
      for (int kt = 0; kt < 4; ++kt) bn[kt] = *(const bfrag*)(Bn + kt * 32);
    }
    f32x4 tmp[4];
#pragma unroll
    for (int m = 0; m < 4; ++m) tmp[m] = (f32x4){0.f, 0.f, 0.f, 0.f};
#pragma unroll
    for (int kt = 0; kt < 4; ++kt)
#pragma unroll
      for (int m = 0; m < 4; ++m)
        tmp[m] = __builtin_amdgcn_mfma_f32_16x16x32_bf16(a[m][kt], bc[kt], tmp[m], 0, 0, 0);
#pragma unroll
    for (int m = 0; m < 4; ++m) {
      f32x4 cf = *(const f32x4*)&coefT[n][m * 16 + quad * 4];
      out[m] += cf * tmp[m];
    }
    if (n + 1 < NOPS) {
#pragma unroll
      for (int kt = 0; kt < 4; ++kt) bc[kt] = bn[kt];
    }
  }
  __syncthreads();

  // ---- P3: AO -> xsb (bf16)
#pragma unroll
  for (int m = 0; m < 4; ++m)
#pragma unroll
    for (int r = 0; r < 4; ++r)
      xsb[m * 16 + quad * 4 + r][w * 16 + mrow] = f2b_bits(out[m][r]);
  __syncthreads();

  // ---- P4 (all 8 waves): mix GEMM + residual + mem term + LN
  // wave w: m-tile = w&3, column half = (w>>2)*64.
  const int mtile = w & 3;
  const int ch = (w >> 2) * 64;
  {
    bfrag a2[4];
#pragma unroll
    for (int kt = 0; kt < 4; ++kt)
      a2[kt] = *(const bfrag*)&xsb[mtile * 16 + mrow][kt * 32 + quad * 8];

    f32x4 acc[4];
#pragma unroll
    for (int i = 0; i < 4; ++i) acc[i] = (f32x4){0.f, 0.f, 0.f, 0.f};
#pragma unroll
    for (int kt = 0; kt < 4; ++kt)
#pragma unroll
      for (int nt = 0; nt < 4; ++nt) {
        bfrag b = *(const bfrag*)(WmixA + (size_t)(ch + nt * 16 + mrow) * DR + kt * 32 + quad * 8);
        acc[nt] = __builtin_amdgcn_mfma_f32_16x16x32_bf16(a2[kt], b, acc[nt], 0, 0, 0);
      }

    float v[4][4];
#pragma unroll
    for (int nt = 0; nt < 4; ++nt) {
      const int col = ch + nt * 16 + mrow;
#pragma unroll
      for (int r = 0; r < 4; ++r) {
        const int t = mtile * 16 + quad * 4 + r;
        float y0 = 0.f;
#pragma unroll
        for (int j = 0; j < 16; ++j) y0 += attn[t][j] * SBws[j * 128 + col];
        v[nt][r] = acc[nt][r] + xsf[t][col] + y0;
      }
    }
    float s[4], q[4];
#pragma unroll
    for (int r = 0; r < 4; ++r) {
      float ps = 0.f, pq = 0.f;
#pragma unroll
      for (int nt = 0; nt < 4; ++nt) { ps += v[nt][r]; pq += v[nt][r] * v[nt][r]; }
      s[r] = ps; q[r] = pq;
    }
#pragma unroll
    for (int m = 1; m < 16; m <<= 1)
#pragma unroll
      for (int r = 0; r < 4; ++r) {
        s[r] += __shfl_xor(s[r], m, 64);
        q[r] += __shfl_xor(q[r], m, 64);
      }
    if (mrow == 0)
#pragma unroll
      for (int r = 0; r < 4; ++r) { partS[w][quad][r] = s[r]; partQ[w][quad][r] = q[r]; }
    __syncthreads();

    float mu[4], rsd[4];
#pragma unroll
    for (int r = 0; r < 4; ++r) {
      float ts = s[r] + partS[w ^ 4][quad][r];
      float tq = q[r] + partQ[w ^ 4][quad][r];
      mu[r] = ts * (1.f / DR);
      float var = tq * (1.f / DR) - mu[r] * mu[r];
      rsd[r] = rsqrtf(var + 1e-5f);
    }
    if (!emit) {
#pragma unroll
      for (int nt = 0; nt < 4; ++nt) {
        const int col = ch + nt * 16 + mrow;
        const float g = gammaF[col], bb = betaF[col];
#pragma unroll
        for (int r = 0; r < 4; ++r) {
          const int t = mtile * 16 + quad * 4 + r;
          X[(size_t)(t0 + t) * DR + col] = (v[nt][r] - mu[r]) * rsd[r] * g + bb;
        }
      }
      return;
    }
#pragma unroll
    for (int nt = 0; nt < 4; ++nt) {
      const int col = ch + nt * 16 + mrow;
      const float g = gammaF[col], bb = betaF[col];
#pragma unroll
      for (int r = 0; r < 4; ++r) {
        const int t = mtile * 16 + quad * 4 + r;
        float val = (v[nt][r] - mu[r]) * rsd[r] * g + bb;
        xsf[t][col] = val;
        xsb[t][col] = f2b_bits(val);
      }
    }
  }
  __syncthreads();   // xsf/xsb now hold final reason

  // ================= fused write signal (pass 2 only) ======================
  for (int p = tid; p < 1024; p += 512) {
    int t = p >> 4, j = p & 15;
    const float4* xr = (const float4*)&xsf[t][0];
    float a2 = 0.f;
#pragma unroll 8
    for (int d4 = 0; d4 < 32; ++d4) {
      float4 x = xr[d4];
      a2 += x.x * Mwss[(d4 * 4 + 0) * 16 + j];
      a2 += x.y * Mwss[(d4 * 4 + 1) * 16 + j];
      a2 += x.z * Mwss[(d4 * 4 + 2) * 16 + j];
      a2 += x.w * Mwss[(d4 * 4 + 3) * 16 + j];
    }
    at2[t][j] = a2 * 0.088388347648318447f;
  }
  __syncthreads();

  // gate (wave 0) || at2 softmax (wave 1)
  if (tid < 64) {
    const float4* xr = (const float4*)&xsf[tid][0];
    float z = 0.f;
#pragma unroll 8
    for (int d4 = 0; d4 < 32; ++d4) {
      float4 x = xr[d4];
      z += x.x * WwgF[d4 * 4 + 0] + x.y * WwgF[d4 * 4 + 1]
         + x.z * WwgF[d4 * 4 + 2] + x.w * WwgF[d4 * 4 + 3];
    }
    gp[tid] = wscF[0] / (1.f + expf(-z));
  } else if (tid < 128) {
    const int t = tid - 64;
    float m = -1e30f;
#pragma unroll
    for (int j = 0; j < 16; ++j) m = fmaxf(m, at2[t][j]);
    float s = 0.f;
#pragma unroll
    for (int j = 0; j < 16; ++j) { float e = expf(at2[t][j] - m); at2[t][j] = e; s += e; }
    float inv = 1.f / s;
#pragma unroll
    for (int j = 0; j < 16; ++j) at2[t][j] *= inv;
  }
  __syncthreads();

  // wv GEMM + combine -> RF (8 waves: same mtile/ch split)
  {
    bfrag a2[4];
#pragma unroll
    for (int kt = 0; kt < 4; ++kt)
      a2[kt] = *(const bfrag*)&xsb[mtile * 16 + mrow][kt * 32 + quad * 8];

    f32x4 acc[4];
#pragma unroll
    for (int i = 0; i < 4; ++i) acc[i] = (f32x4){0.f, 0.f, 0.f, 0.f};
#pragma unroll
    for (int kt = 0; kt < 4; ++kt)
#pragma unroll
      for (int nt = 0; nt < 4; ++nt) {
        bfrag b = *(const bfrag*)(WwvB + (size_t)(ch + nt * 16 + mrow) * DR + kt * 32 + quad * 8);
        acc[nt] = __builtin_amdgcn_mfma_f32_16x16x32_bf16(a2[kt], b, acc[nt], 0, 0, 0);
      }

    const float c01 = wscF[0] * 0.1f;
#pragma unroll
    for (int nt = 0; nt < 4; ++nt) {
      const int col = ch + nt * 16 + mrow;
#pragma unroll
      for (int r = 0; r < 4; ++r) {
        const int t = mtile * 16 + quad * 4 + r;
        float mo = 0.f;
#pragma unroll
        for (int j = 0; j < 16; ++j) mo += at2[t][j] * slotss[j * DR + col];
        float val = xsf[t][col] + gp[t] * acc[nt][r] + c01 * mo;
        RF[(size_t)(t0 + t) * DR + col] = f2b_bits(val);
      }
    }
  }
}

// ---------- up projection + residual; Rf staged in LDS (union with cs) -----
__global__ __launch_bounds__(256) void k_up(const ushort* __restrict__ Rf,
                                            const ushort* __restrict__ WuE,
                                            const float* __restrict__ hidden,
                                            float* __restrict__ out) {
  __shared__ float cs[64][132];        // 33.8 KB; first 17.4 KB doubles as stg
  ushort (*stg)[136] = reinterpret_cast<ushort(*)[136]>(&cs[0][0]);

  const int wave = threadIdx.x >> 6, lane = threadIdx.x & 63;
  const int quad = lane >> 4, mrow = lane & 15;
  const int mt = blockIdx.x >> 3, ngrp = blockIdx.x & 7;
  const int m0b = mt * 64;
  const int c0 = ngrp * 128;

  // stage Rf tile (64 x 128 bf16) coalesced: consecutive tid -> consecutive 16B
  for (int i = threadIdx.x; i < 1024; i += 256) {
    const int r = i >> 4, c = (i & 15) * 8;
    *(bfrag*)&stg[r][c] = *(const bfrag*)(Rf + (size_t)(m0b + r) * DR + c);
  }
  __syncthreads();

  // A-fragments -> registers (before cs overwrites stg)
  bfrag a[4];
#pragma unroll
  for (int kt = 0; kt < 4; ++kt)
    a[kt] = *(const bfrag*)&stg[wave * 16 + mrow][kt * 32 + quad * 8];
  __syncthreads();   // all frag reads done before any cs write

  f32x4 acc[8];
#pragma unroll
  for (int i = 0; i < 8; ++i) acc[i] = (f32x4){0.f, 0.f, 0.f, 0.f};

#pragma unroll
  for (int kt = 0; kt < 4; ++kt) {
#pragma unroll
    for (int nt = 0; nt < 8; ++nt) {
      const ushort* Bp = WuE + (size_t)(c0 + nt * 16 + mrow) * DR + kt * 32 + quad * 8;
      bfrag b = *(const bfrag*)Bp;
      acc[nt] = __builtin_amdgcn_mfma_f32_16x16x32_bf16(a[kt], b, acc[nt], 0, 0, 0);
    }
  }
#pragma unroll
  for (int nt = 0; nt < 8; ++nt)
#pragma unroll
    for (int r = 0; r < 4; ++r)
      cs[wave * 16 + quad * 4 + r][nt * 16 + mrow] = acc[nt][r];
  __syncthreads();

#pragma unroll
  for (int k = 0; k < 8; ++k) {
    const int i = threadIdx.x + k * 256;
    const int t = i >> 5, c4 = (i & 31) * 4;
    const size_t idx = (size_t)(m0b + t) * DM + c0 + c4;
    float4 h = *(const float4*)(hidden + idx);
    float4 v;
    v.x = h.x + cs[t][c4];
    v.y = h.y + cs[t][c4 + 1];
    v.z = h.z + cs[t][c4 + 2];
    v.w = h.w + cs[t][c4 + 3];
    *(float4*)(out + idx) = v;
  }
}

// ---------------------------------------------------------------------------
extern "C" void kernel_launch(void* const* d_in, const int* in_sizes, int n_in,
                              void* d_out, int out_size, void* d_ws, size_t ws_size,
                              hipStream_t stream) {
  int ns[20]; int nn = 0; int lastsc = -1;
  for (int i = 0; i < n_in; ++i) {
    if (in_sizes[i] == 1) lastsc = i;
    else if (nn < 20) ns[nn++] = i;
  }
  int iH = 0, iWd = 2, iWu = 3, iOps = 4, iWr = 5, iSl = 6, iRe = 7,
      iWk = 8, iWg = 9, iWv = 10, iMx = 11, iG = 12, iB = 13;
  if (nn >= 13) {
    iH  = ns[0];  iWd = ns[1];  iWu = ns[2];  iOps = ns[3]; iWr = ns[4];
    iSl = ns[5];  iRe = ns[6];  iWk = ns[7];  iWg = ns[8];  iWv = ns[9];
    iMx = ns[10]; iG  = ns[11]; iB  = ns[12];
  }
  const float* hidden   = (const float*)d_in[iH];
  const float* W_down   = (const float*)d_in[iWd];
  const float* W_up     = (const float*)d_in[iWu];
  const float* opsw     = (const float*)d_in[iOps];
  const float* W_router = (const float*)d_in[iWr];
  const float* slots    = (const float*)d_in[iSl];
  const float* W_read   = (const float*)d_in[iRe];
  const float* W_wk     = (const float*)d_in[iWk];
  const float* W_wg     = (const float*)d_in[iWg];
  const float* W_wv     = (const float*)d_in[iWv];
  const float* W_mix    = (const float*)d_in[iMx];
  const float* lng      = (const float*)d_in[iG];
  const float* lnb      = (const float*)d_in[iB];
  const float* wscale   = (lastsc >= 0) ? (const float*)d_in[lastsc] : (const float*)d_in[iG];
  const int has_wsc     = (lastsc >= 0) ? 1 : 0;

  char* ws = (char*)d_ws;
  float*  sums   = (float*)(ws + OFF_SUMS);
  float*  opsSc  = (float*)(ws + OFF_OPSSC);
  ushort* WdE    = (ushort*)(ws + OFF_WDE);
  ushort* WuE    = (ushort*)(ws + OFF_WUE);
  float*  WrT    = (float*)(ws + OFF_WRT);
  ushort* opsB   = (ushort*)(ws + OFF_OPSB);
  ushort* WmixA  = (ushort*)(ws + OFF_WMIXA);
  ushort* WwvB   = (ushort*)(ws + OFF_WWVB);
  float*  Mrs    = (float*)(ws + OFF_MRS);
  float*  Mws    = (float*)(ws + OFF_MWS);
  float*  SBw    = (float*)(ws + OFF_SB);
  float*  slotsF = (float*)(ws + OFF_SLOTS);
  float*  WwgF   = (float*)(ws + OFF_WWG);
  float*  gammaF = (float*)(ws + OFF_GAMMA);
  float*  betaF  = (float*)(ws + OFF_BETA);
  float*  wscF   = (float*)(ws + OFF_WSC);
  ushort* RF     = (ushort*)(ws + OFF_RF);

  float* X = (float*)d_out;

  hipMemsetAsync(ws + OFF_SUMS, 0, 256, stream);
  k_absum_all<<<dim3(8, 35), 256, 0, stream>>>(W_down, W_router, W_up, opsw, sums);
  k_build<<<3250, 256, 0, stream>>>(W_down, W_up, W_router, opsw, W_read, W_wk, W_wg,
                                    W_wv, W_mix, slots, lng, lnb, wscale, has_wsc,
                                    sums, WdE, WuE, WrT, opsB, opsSc, WmixA, WwvB,
                                    Mrs, Mws, SBw, slotsF, WwgF, gammaF, betaF, wscF);
  k_down<<<256, 512, 0, stream>>>(hidden, WdE, X);
  k_pass2<<<256, 512, 0, stream>>>(X, RF, 0, WrT, opsB, opsSc, WmixA, Mrs, SBw,
                                   gammaF, betaF, WwvB, Mws, slotsF, WwgF, wscF);
  k_pass2<<<256, 512, 0, stream>>>(X, RF, 1, WrT, opsB, opsSc, WmixA, Mrs, SBw,
                                   gammaF, betaF, WwvB, Mws, slotsF, WwgF, wscF);
  k_up<<<2048, 256, 0, stream>>>(RF, WuE, hidden, X);
}

// Round 11
// 325.411 us; speedup vs baseline: 1.0808x; 1.0808x over previous
//
#include <hip/hip_runtime.h>

// ---------------------------------------------------------------------------
// RCSM engine, MI355X/gfx950.  FP32 in/out.  Round 19:
//  * r18 post-mortem: both r18 changes reverted. absum-35 blocks run
//    concurrently (per-CU BW x 35, ~5 us — not 20); k_up staging serialized
//    A/B load overlap (Rf is L2-hot, scatter was free).  Anchor = r17 (344).
//  * NEW: attn + at2 slot-score GEMVs -> MFMA (waves 0-3, 4 mfma each) via
//    bf16 MrsE/MwsE [16][128] built in k_build from W_read/W_wk/slots
//    (NOT from Mrs: same-dispatch race).  bf16-safe: scores feed softmax
//    then ~0.01-scale slots; error ~1e-4 << absmax 0.031.  Router logits
//    stay fp32 (topk flip risk).  Mrss/Mwss staging dropped (-16 KB LDS).
//  * lg GEMV: 2-way accumulator split (dep chain 128 -> 64).
//  * k_pass2 P2/P4 structure, k_down, k_up, absum: byte-identical to r17.
// ---------------------------------------------------------------------------

#define DR   128
#define DM   1024
#define NTOK 16384
#define NOPS 32
#define COEF (1e-5f / 32.f)

typedef __attribute__((ext_vector_type(8))) short bfrag;   // 8 x bf16 bits
typedef __attribute__((ext_vector_type(4))) float f32x4;

__device__ __forceinline__ ushort f2b_bits(float f) {
  union { float f; uint i; } c; c.f = f;
  uint x = c.i;
  return (ushort)((x + 0x7fffu + ((x >> 16) & 1u)) >> 16);   // RNE
}
__device__ __forceinline__ float qeff(float w, float s) {
  float q = rintf(w / s);
  q = fminf(1.f, fmaxf(-1.f, q));
  return q * s;
}
__device__ __forceinline__ float waveRed(float v) {
#pragma unroll
  for (int m = 32; m > 0; m >>= 1) v += __shfl_xor(v, m, 64);
  return v;
}

// ---------------- ws layout (bytes) ----------------------------------------
#define OFF_SUMS    0
#define OFF_OPSSC   256
#define OFF_WDE     512
#define OFF_WUE     (OFF_WDE + 262144)
#define OFF_WRT     (OFF_WUE + 262144)
#define OFF_OPSB    (OFF_WRT + 16384)
#define OFF_WMIXA   (OFF_OPSB + 1048576)
#define OFF_WWVB    (OFF_WMIXA + 32768)
#define OFF_MRS     (OFF_WWVB + 32768)
#define OFF_MWS     (OFF_MRS + 8192)
#define OFF_SB      (OFF_MWS + 8192)
#define OFF_SLOTS   (OFF_SB + 8192)
#define OFF_WWG     (OFF_SLOTS + 8192)
#define OFF_GAMMA   (OFF_WWG + 512)
#define OFF_BETA    (OFF_GAMMA + 512)
#define OFF_WSC     (OFF_BETA + 512)
#define OFF_MRSE    (OFF_WSC + 256)
#define OFF_MWSE    (OFF_MRSE + 4096)
#define OFF_RF      (OFF_MWSE + 4096)
#define WS_TOTAL    (OFF_RF + 4194304)

// ----------------- abs-sum: one block per tensor (r17) ---------------------
__global__ __launch_bounds__(1024) void k_absum_all(
    const float* __restrict__ W_down, const float* __restrict__ W_router,
    const float* __restrict__ W_up, const float* __restrict__ ops,
    float* __restrict__ sums) {
  __shared__ float ws16[16];
  const int y = blockIdx.x;
  const int tid = threadIdx.x;
  const float* src; int n;
  if (y == 0)      { src = W_down;   n = 131072; }
  else if (y == 1) { src = W_router; n = 4096;   }
  else if (y == 2) { src = W_up;     n = 131072; }
  else             { src = ops + (size_t)(y - 3) * 16384; n = 16384; }
  float s = 0.f;
  for (int i = tid * 4; i < n; i += 4096) {
    float4 v = *(const float4*)(src + i);
    s += fabsf(v.x) + fabsf(v.y) + fabsf(v.z) + fabsf(v.w);
  }
  s = waveRed(s);
  const int lane = tid & 63, wv = tid >> 6;
  if (lane == 0) ws16[wv] = s;
  __syncthreads();
  if (tid == 0) {
    float t = 0.f;
#pragma unroll
    for (int i = 0; i < 16; ++i) t += ws16[i];
    sums[y] = t;
  }
}

// --------------------------- weight build ----------------------------------
__global__ __launch_bounds__(256) void k_build(
    const float* __restrict__ W_down, const float* __restrict__ W_up,
    const float* __restrict__ W_router, const float* __restrict__ ops,
    const float* __restrict__ W_read, const float* __restrict__ W_wk,
    const float* __restrict__ W_wg, const float* __restrict__ W_wv,
    const float* __restrict__ W_mix, const float* __restrict__ slots,
    const float* __restrict__ gamma, const float* __restrict__ beta,
    const float* __restrict__ wscale, int has_wsc, const float* __restrict__ sums,
    ushort* __restrict__ WdE, ushort* __restrict__ WuE, float* __restrict__ WrT,
    ushort* __restrict__ opsB, float* __restrict__ opsScale,
    ushort* __restrict__ WmixA, ushort* __restrict__ WwvB,
    float* __restrict__ Mrs, float* __restrict__ Mws, float* __restrict__ SBw,
    float* __restrict__ slotsF, float* __restrict__ WwgF,
    float* __restrict__ gammaF, float* __restrict__ betaF, float* __restrict__ wscF,
    ushort* __restrict__ MrsE, ushort* __restrict__ MwsE) {
  int id = blockIdx.x * 256 + threadIdx.x;
  const float s_wd = fmaxf(sums[0] * (1.f / 131072.f), 1e-5f);
  const float s_wr = fmaxf(sums[1] * (1.f / 4096.f), 1e-5f);
  const float s_wu = fmaxf(sums[2] * (1.f / 131072.f), 1e-5f);

  if (id < 131072) { WdE[id] = f2b_bits(qeff(W_down[id], s_wd)); return; }
  id -= 131072;
  if (id < 131072) { WuE[id] = f2b_bits(qeff(W_up[id], s_wu)); return; }
  id -= 131072;
  if (id < 4096) {
    int d = id >> 5, n = id & 31;
    WrT[id] = qeff(W_router[n * DR + d], s_wr);
    return;
  }
  id -= 4096;
  if (id < 524288) {
    int n = id >> 14;
    float s = fmaxf(sums[3 + n] * (1.f / 16384.f), 1e-5f);
    float q = rintf(ops[id] / s);
    q = fminf(1.f, fmaxf(-1.f, q));
    opsB[id] = f2b_bits(q);
    return;
  }
  id -= 524288;
  if (id < 32) { opsScale[id] = fmaxf(sums[3 + id] * (1.f / 16384.f), 1e-5f); return; }
  id -= 32;
  if (id < 16384) {
    int r = id >> 7, o = id & 127;
    WmixA[id] = f2b_bits(W_mix[r * 256 + o]);
    return;
  }
  id -= 16384;
  if (id < 16384) { WwvB[id] = f2b_bits(W_wv[id]); return; }
  id -= 16384;
  if (id < 2048) {
    int d = id >> 4, j = id & 15;
    float a = 0.f;
#pragma unroll 8
    for (int o = 0; o < DR; ++o) a += W_read[o * DR + d] * slots[j * DR + o];
    Mrs[id] = a;
    return;
  }
  id -= 2048;
  if (id < 2048) {
    int d = id >> 4, j = id & 15;
    float a = 0.f;
#pragma unroll 8
    for (int o = 0; o < DR; ++o) a += W_wk[o * DR + d] * slots[j * DR + o];
    Mws[id] = a;
    return;
  }
  id -= 2048;
  if (id < 2048) {
    int j = id >> 7, r = id & 127;
    float a = 0.f;
#pragma unroll 8
    for (int o = 0; o < DR; ++o) a += slots[j * DR + o] * W_mix[r * 256 + 128 + o];
    SBw[id] = a;
    return;
  }
  id -= 2048;
  if (id < 2048) { slotsF[id] = slots[id]; return; }
  id -= 2048;
  if (id < 128) { WwgF[id] = W_wg[id]; return; }
  id -= 128;
  if (id < 128) { gammaF[id] = gamma[id]; return; }
  id -= 128;
  if (id < 128) { betaF[id] = beta[id]; return; }
  id -= 128;
  if (id < 2048) {           // MrsE[j][d] bf16 (B-operand layout for MFMA)
    int j = id >> 7, d = id & 127;
    float a = 0.f;
#pragma unroll 8
    for (int o = 0; o < DR; ++o) a += W_read[o * DR + d] * slots[j * DR + o];
    MrsE[id] = f2b_bits(a);
    return;
  }
  id -= 2048;
  if (id < 2048) {           // MwsE[j][d] bf16
    int j = id >> 7, d = id & 127;
    float a = 0.f;
#pragma unroll 8
    for (int o = 0; o < DR; ++o) a += W_wk[o * DR + d] * slots[j * DR + o];
    MwsE[id] = f2b_bits(a);
    return;
  }
  id -= 2048;
  if (id == 0) { wscF[0] = has_wsc ? wscale[0] : 0.01f; }
}

// ------ down projection: LDS-staged coalesced MFMA GEMM --------------------
__global__ __launch_bounds__(512) void k_down(const float* __restrict__ hidden,
                                              const ushort* __restrict__ WdE,
                                              float* __restrict__ X) {
  __shared__ ushort stg[64][136];      // 17.4 KB staging (bf16, padded)

  const int tid = threadIdx.x;
  const int w = tid >> 6, lane = tid & 63;
  const int quad = lane >> 4, mrow = lane & 15;
  const int t0 = blockIdx.x * 64;

  f32x4 dacc[4];
#pragma unroll
  for (int m = 0; m < 4; ++m) dacc[m] = (f32x4){0.f, 0.f, 0.f, 0.f};

  for (int kc = 0; kc < 8; ++kc) {
    for (int i = tid; i < 2048; i += 512) {
      int t = i >> 5, c = (i & 31) * 4;
      float4 v = *(const float4*)(hidden + (size_t)(t0 + t) * DM + kc * 128 + c);
      stg[t][c] = f2b_bits(v.x); stg[t][c + 1] = f2b_bits(v.y);
      stg[t][c + 2] = f2b_bits(v.z); stg[t][c + 3] = f2b_bits(v.w);
    }
    __syncthreads();
#pragma unroll
    for (int kt = 0; kt < 4; ++kt) {
      bfrag b = *(const bfrag*)(WdE + (size_t)(w * 16 + mrow) * DM + kc * 128 + kt * 32 + quad * 8);
#pragma unroll
      for (int m = 0; m < 4; ++m) {
        bfrag a = *(const bfrag*)&stg[m * 16 + mrow][kt * 32 + quad * 8];
        dacc[m] = __builtin_amdgcn_mfma_f32_16x16x32_bf16(a, b, dacc[m], 0, 0, 0);
      }
    }
    __syncthreads();
  }
#pragma unroll
  for (int m = 0; m < 4; ++m)
#pragma unroll
    for (int r = 0; r < 4; ++r)
      X[(size_t)(t0 + m * 16 + quad * 4 + r) * DR + w * 16 + mrow] = dacc[m][r];
}

// -------------------------- fused pass kernel ------------------------------
// 256 blocks x 512 threads; 64 tokens/block.  WrT/SBw/slots staged in LDS;
// attn/at2 slot scores via MFMA (bf16 MrsE/MwsE, waves 0-3).
__global__ __launch_bounds__(512) void k_pass2(
    float* __restrict__ X, ushort* __restrict__ RF, int emit,
    const float* __restrict__ WrT, const ushort* __restrict__ opsB,
    const float* __restrict__ opsScale, const ushort* __restrict__ WmixA,
    const ushort* __restrict__ MrsE, const float* __restrict__ SBw,
    const float* __restrict__ gammaF, const float* __restrict__ betaF,
    const ushort* __restrict__ WwvB, const ushort* __restrict__ MwsE,
    const float* __restrict__ slotsF, const float* __restrict__ WwgF,
    const float* __restrict__ wscF) {
  __shared__ float  xsf[64][132];      // 33.8 KB (pad: col access 2-way, free)
  __shared__ ushort xsb[64][136];      // 17 KB
  __shared__ float  lg[64][33];        // 8.4 KB
  __shared__ float  coefT[32][64];     // 8 KB
  __shared__ float  attn[64][17];      // 4.3 KB
  __shared__ float  at2[64][17];       // 4.3 KB
  __shared__ float  WrTs[4096];        // 16 KB  (staged weight tables)
  __shared__ float  SBws[2048];        // 8 KB
  __shared__ float  slotss[2048];      // 8 KB
  __shared__ int    seli[64][2];
  __shared__ float  selw[64][2];
  __shared__ float  gp[64];
  __shared__ float  partS[8][4][4];    // cross-wave LN partials
  __shared__ float  partQ[8][4][4];

  const int tid = threadIdx.x;
  const int w = tid >> 6, lane = tid & 63;
  const int quad = lane >> 4, mrow = lane & 15;
  const int t0 = blockIdx.x * 64;

  // ---- P0: stage weight tables + X tile -> LDS
  {
    float4* d = (float4*)WrTs;
    const float4* s = (const float4*)WrT;
    for (int i = tid; i < 1024; i += 512) d[i] = s[i];
    ((float4*)SBws)[tid]   = ((const float4*)SBw)[tid];
    ((float4*)slotss)[tid] = ((const float4*)slotsF)[tid];
  }
  for (int i = tid; i < 2048; i += 512) {
    float4 v = *(const float4*)(X + (size_t)t0 * DR + i * 4);
    int t = i >> 5, c = (i & 31) * 4;
    xsf[t][c] = v.x; xsf[t][c + 1] = v.y; xsf[t][c + 2] = v.z; xsf[t][c + 3] = v.w;
    xsb[t][c] = f2b_bits(v.x); xsb[t][c + 1] = f2b_bits(v.y);
    xsb[t][c + 2] = f2b_bits(v.z); xsb[t][c + 3] = f2b_bits(v.w);
  }
  __syncthreads();

  // ---- P1: router logits (fp32 GEMV, 2-chain) + attn scores (MFMA)
  for (int p = tid; p < 2048; p += 512) {
    int t = p >> 5, n = p & 31;
    const float4* xr = (const float4*)&xsf[t][0];
    float a0 = 0.f, a1 = 0.f;
#pragma unroll
    for (int d4 = 0; d4 < 32; d4 += 2) {
      float4 x0 = xr[d4];
      float4 x1 = xr[d4 + 1];
      a0 += x0.x * WrTs[(d4 * 4 + 0) * 32 + n] + x0.y * WrTs[(d4 * 4 + 1) * 32 + n]
          + x0.z * WrTs[(d4 * 4 + 2) * 32 + n] + x0.w * WrTs[(d4 * 4 + 3) * 32 + n];
      a1 += x1.x * WrTs[(d4 * 4 + 4) * 32 + n] + x1.y * WrTs[(d4 * 4 + 5) * 32 + n]
          + x1.z * WrTs[(d4 * 4 + 6) * 32 + n] + x1.w * WrTs[(d4 * 4 + 7) * 32 + n];
    }
    lg[t][n] = a0 + a1;
  }
  if (w < 4) {                         // attn = X @ MrsE^T via MFMA
    f32x4 acc = (f32x4){0.f, 0.f, 0.f, 0.f};
#pragma unroll
    for (int kt = 0; kt < 4; ++kt) {
      bfrag av = *(const bfrag*)&xsb[w * 16 + mrow][kt * 32 + quad * 8];
      bfrag bv = *(const bfrag*)(MrsE + (size_t)mrow * DR + kt * 32 + quad * 8);
      acc = __builtin_amdgcn_mfma_f32_16x16x32_bf16(av, bv, acc, 0, 0, 0);
    }
#pragma unroll
    for (int r = 0; r < 4; ++r)
      attn[w * 16 + quad * 4 + r][mrow] = acc[r] * 0.088388347648318447f;
  }
  __syncthreads();

  // topk (wave 0) || attn softmax (wave 1): parallel serial sections
  if (tid < 64) {
    float v0 = -1e30f; int i0 = 0;
#pragma unroll
    for (int n = 0; n < 32; ++n) { float v = lg[tid][n]; if (v > v0) { v0 = v; i0 = n; } }
    float v1 = -1e30f; int i1 = 0;
#pragma unroll
    for (int n = 0; n < 32; ++n)
      if (n != i0) { float v = lg[tid][n]; if (v > v1) { v1 = v; i1 = n; } }
    float e = expf(v1 - v0);
    float w0 = 1.f / (1.f + e);
    seli[tid][0] = i0; seli[tid][1] = i1;
    selw[tid][0] = w0; selw[tid][1] = e * w0;
  } else if (tid < 128) {
    const int t = tid - 64;
    float m = -1e30f;
#pragma unroll
    for (int j = 0; j < 16; ++j) m = fmaxf(m, attn[t][j]);
    float s = 0.f;
#pragma unroll
    for (int j = 0; j < 16; ++j) { float ee = expf(attn[t][j] - m); attn[t][j] = ee; s += ee; }
    float inv = 1.f / s;
#pragma unroll
    for (int j = 0; j < 16; ++j) attn[t][j] *= inv;
  }
  __syncthreads();

  for (int p = tid; p < 2048; p += 512) {
    int n = p >> 6, t = p & 63;
    float cf = COEF;
    if (n == seli[t][0]) cf += selw[t][0];
    if (n == seli[t][1]) cf += selw[t][1];
    coefT[n][t] = cf * opsScale[n];
  }
  __syncthreads();

  // ---- P2: 32-op MFMA GEMM.  Wave w owns cols w*16..+15, all 4 m-tiles.
  bfrag a[4][4];
#pragma unroll
  for (int m = 0; m < 4; ++m)
#pragma unroll
    for (int kt = 0; kt < 4; ++kt)
      a[m][kt] = *(const bfrag*)&xsb[m * 16 + mrow][kt * 32 + quad * 8];

  const ushort* Bp = opsB + (size_t)(w * 16 + mrow) * DR + quad * 8;
  bfrag bc[4], bn[4];
#pragma unroll
  for (int kt = 0; kt < 4; ++kt) bc[kt] = *(const bfrag*)(Bp + kt * 32);

  f32x4 out[4];
#pragma unroll
  for (int m = 0; m < 4; ++m) out[m] = (f32x4){0.f, 0.f, 0.f, 0.f};

  for (int n = 0; n < NOPS; ++n) {
    if (n + 1 < NOPS) {
      const ushort* Bn = Bp + (size_t)(n + 1) * (DR * DR);
#pragma unroll
      for (int kt = 0; kt < 4; ++kt) bn[kt] = *(const bfrag*)(Bn + kt * 32);
    }
    f32x4 tmp[4];
#pragma unroll
    for (int m = 0; m < 4; ++m) tmp[m] = (f32x4){0.f, 0.f, 0.f, 0.f};
#pragma unroll
    for (int kt = 0; kt < 4; ++kt)
#pragma unroll
      for (int m = 0; m < 4; ++m)
        tmp[m] = __builtin_amdgcn_mfma_f32_16x16x32_bf16(a[m][kt], bc[kt], tmp[m], 0, 0, 0);
#pragma unroll
    for (int m = 0; m < 4; ++m) {
      f32x4 cf = *(const f32x4*)&coefT[n][m * 16 + quad * 4];
      out[m] += cf * tmp[m];
    }
    if (n + 1 < NOPS) {
#pragma unroll
      for (int kt = 0; kt < 4; ++kt) bc[kt] = bn[kt];
    }
  }
  __syncthreads();

  // ---- P3: AO -> xsb (bf16)
#pragma unroll
  for (int m = 0; m < 4; ++m)
#pragma unroll
    for (int r = 0; r < 4; ++r)
      xsb[m * 16 + quad * 4 + r][w * 16 + mrow] = f2b_bits(out[m][r]);
  __syncthreads();

  // ---- P4 (all 8 waves): mix GEMM + residual + mem term + LN
  const int mtile = w & 3;
  const int ch = (w >> 2) * 64;
  {
    bfrag a2[4];
#pragma unroll
    for (int kt = 0; kt < 4; ++kt)
      a2[kt] = *(const bfrag*)&xsb[mtile * 16 + mrow][kt * 32 + quad * 8];

    f32x4 acc[4];
#pragma unroll
    for (int i = 0; i < 4; ++i) acc[i] = (f32x4){0.f, 0.f, 0.f, 0.f};
#pragma unroll
    for (int kt = 0; kt < 4; ++kt)
#pragma unroll
      for (int nt = 0; nt < 4; ++nt) {
        bfrag b = *(const bfrag*)(WmixA + (size_t)(ch + nt * 16 + mrow) * DR + kt * 32 + quad * 8);
        acc[nt] = __builtin_amdgcn_mfma_f32_16x16x32_bf16(a2[kt], b, acc[nt], 0, 0, 0);
      }

    float v[4][4];
#pragma unroll
    for (int nt = 0; nt < 4; ++nt) {
      const int col = ch + nt * 16 + mrow;
#pragma unroll
      for (int r = 0; r < 4; ++r) {
        const int t = mtile * 16 + quad * 4 + r;
        float y0 = 0.f;
#pragma unroll
        for (int j = 0; j < 16; ++j) y0 += attn[t][j] * SBws[j * 128 + col];
        v[nt][r] = acc[nt][r] + xsf[t][col] + y0;
      }
    }
    float s[4], q[4];
#pragma unroll
    for (int r = 0; r < 4; ++r) {
      float ps = 0.f, pq = 0.f;
#pragma unroll
      for (int nt = 0; nt < 4; ++nt) { ps += v[nt][r]; pq += v[nt][r] * v[nt][r]; }
      s[r] = ps; q[r] = pq;
    }
#pragma unroll
    for (int m = 1; m < 16; m <<= 1)
#pragma unroll
      for (int r = 0; r < 4; ++r) {
        s[r] += __shfl_xor(s[r], m, 64);
        q[r] += __shfl_xor(q[r], m, 64);
      }
    if (mrow == 0)
#pragma unroll
      for (int r = 0; r < 4; ++r) { partS[w][quad][r] = s[r]; partQ[w][quad][r] = q[r]; }
    __syncthreads();

    float mu[4], rsd[4];
#pragma unroll
    for (int r = 0; r < 4; ++r) {
      float ts = s[r] + partS[w ^ 4][quad][r];
      float tq = q[r] + partQ[w ^ 4][quad][r];
      mu[r] = ts * (1.f / DR);
      float var = tq * (1.f / DR) - mu[r] * mu[r];
      rsd[r] = rsqrtf(var + 1e-5f);
    }
    if (!emit) {
#pragma unroll
      for (int nt = 0; nt < 4; ++nt) {
        const int col = ch + nt * 16 + mrow;
        const float g = gammaF[col], bb = betaF[col];
#pragma unroll
        for (int r = 0; r < 4; ++r) {
          const int t = mtile * 16 + quad * 4 + r;
          X[(size_t)(t0 + t) * DR + col] = (v[nt][r] - mu[r]) * rsd[r] * g + bb;
        }
      }
      return;
    }
#pragma unroll
    for (int nt = 0; nt < 4; ++nt) {
      const int col = ch + nt * 16 + mrow;
      const float g = gammaF[col], bb = betaF[col];
#pragma unroll
      for (int r = 0; r < 4; ++r) {
        const int t = mtile * 16 + quad * 4 + r;
        float val = (v[nt][r] - mu[r]) * rsd[r] * g + bb;
        xsf[t][col] = val;
        xsb[t][col] = f2b_bits(val);
      }
    }
  }
  __syncthreads();   // xsf/xsb now hold final reason

  // ================= fused write signal (pass 2 only) ======================
  if (w < 4) {                         // at2 = reason @ MwsE^T via MFMA
    f32x4 acc = (f32x4){0.f, 0.f, 0.f, 0.f};
#pragma unroll
    for (int kt = 0; kt < 4; ++kt) {
      bfrag av = *(const bfrag*)&xsb[w * 16 + mrow][kt * 32 + quad * 8];
      bfrag bv = *(const bfrag*)(MwsE + (size_t)mrow * DR + kt * 32 + quad * 8);
      acc = __builtin_amdgcn_mfma_f32_16x16x32_bf16(av, bv, acc, 0, 0, 0);
    }
#pragma unroll
    for (int r = 0; r < 4; ++r)
      at2[w * 16 + quad * 4 + r][mrow] = acc[r] * 0.088388347648318447f;
  }
  __syncthreads();

  // gate (wave 0) || at2 softmax (wave 1)
  if (tid < 64) {
    const float4* xr = (const float4*)&xsf[tid][0];
    float z = 0.f;
#pragma unroll 8
    for (int d4 = 0; d4 < 32; ++d4) {
      float4 x = xr[d4];
      z += x.x * WwgF[d4 * 4 + 0] + x.y * WwgF[d4 * 4 + 1]
         + x.z * WwgF[d4 * 4 + 2] + x.w * WwgF[d4 * 4 + 3];
    }
    gp[tid] = wscF[0] / (1.f + expf(-z));
  } else if (tid < 128) {
    const int t = tid - 64;
    float m = -1e30f;
#pragma unroll
    for (int j = 0; j < 16; ++j) m = fmaxf(m, at2[t][j]);
    float s = 0.f;
#pragma unroll
    for (int j = 0; j < 16; ++j) { float e = expf(at2[t][j] - m); at2[t][j] = e; s += e; }
    float inv = 1.f / s;
#pragma unroll
    for (int j = 0; j < 16; ++j) at2[t][j] *= inv;
  }
  __syncthreads();

  // wv GEMM + combine -> RF (8 waves: same mtile/ch split)
  {
    bfrag a2[4];
#pragma unroll
    for (int kt = 0; kt < 4; ++kt)
      a2[kt] = *(const bfrag*)&xsb[mtile * 16 + mrow][kt * 32 + quad * 8];

    f32x4 acc[4];
#pragma unroll
    for (int i = 0; i < 4; ++i) acc[i] = (f32x4){0.f, 0.f, 0.f, 0.f};
#pragma unroll
    for (int kt = 0; kt < 4; ++kt)
#pragma unroll
      for (int nt = 0; nt < 4; ++nt) {
        bfrag b = *(const bfrag*)(WwvB + (size_t)(ch + nt * 16 + mrow) * DR + kt * 32 + quad * 8);
        acc[nt] = __builtin_amdgcn_mfma_f32_16x16x32_bf16(a2[kt], b, acc[nt], 0, 0, 0);
      }

    const float c01 = wscF[0] * 0.1f;
#pragma unroll
    for (int nt = 0; nt < 4; ++nt) {
      const int col = ch + nt * 16 + mrow;
#pragma unroll
      for (int r = 0; r < 4; ++r) {
        const int t = mtile * 16 + quad * 4 + r;
        float mo = 0.f;
#pragma unroll
        for (int j = 0; j < 16; ++j) mo += at2[t][j] * slotss[j * DR + col];
        float val = xsf[t][col] + gp[t] * acc[nt][r] + c01 * mo;
        RF[(size_t)(t0 + t) * DR + col] = f2b_bits(val);
      }
    }
  }
}

// ---------- up projection + residual (r17 form) ----------------------------
__global__ __launch_bounds__(256) void k_up(const ushort* __restrict__ Rf,
                                            const ushort* __restrict__ WuE,
                                            const float* __restrict__ hidden,
                                            float* __restrict__ out) {
  __shared__ float cs[64][132];

  const int wave = threadIdx.x >> 6, lane = threadIdx.x & 63;
  const int quad = lane >> 4, mrow = lane & 15;
  const int mt = blockIdx.x >> 3, ngrp = blockIdx.x & 7;
  const int m0b = mt * 64;
  const int m0 = m0b + wave * 16;
  const int c0 = ngrp * 128;

  f32x4 acc[8];
#pragma unroll
  for (int i = 0; i < 8; ++i) acc[i] = (f32x4){0.f, 0.f, 0.f, 0.f};

  const ushort* Ap = Rf + (size_t)(m0 + mrow) * DR + quad * 8;
#pragma unroll
  for (int kt = 0; kt < 4; ++kt) {
    bfrag a = *(const bfrag*)(Ap + kt * 32);
#pragma unroll
    for (int nt = 0; nt < 8; ++nt) {
      const ushort* Bp = WuE + (size_t)(c0 + nt * 16 + mrow) * DR + kt * 32 + quad * 8;
      bfrag b = *(const bfrag*)Bp;
      acc[nt] = __builtin_amdgcn_mfma_f32_16x16x32_bf16(a, b, acc[nt], 0, 0, 0);
    }
  }
#pragma unroll
  for (int nt = 0; nt < 8; ++nt)
#pragma unroll
    for (int r = 0; r < 4; ++r)
      cs[wave * 16 + quad * 4 + r][nt * 16 + mrow] = acc[nt][r];
  __syncthreads();

#pragma unroll
  for (int k = 0; k < 8; ++k) {
    const int i = threadIdx.x + k * 256;
    const int t = i >> 5, c4 = (i & 31) * 4;
    const size_t idx = (size_t)(m0b + t) * DM + c0 + c4;
    float4 h = *(const float4*)(hidden + idx);
    float4 v;
    v.x = h.x + cs[t][c4];
    v.y = h.y + cs[t][c4 + 1];
    v.z = h.z + cs[t][c4 + 2];
    v.w = h.w + cs[t][c4 + 3];
    *(float4*)(out + idx) = v;
  }
}

// ---------------------------------------------------------------------------
extern "C" void kernel_launch(void* const* d_in, const int* in_sizes, int n_in,
                              void* d_out, int out_size, void* d_ws, size_t ws_size,
                              hipStream_t stream) {
  int ns[20]; int nn = 0; int lastsc = -1;
  for (int i = 0; i < n_in; ++i) {
    if (in_sizes[i] == 1) lastsc = i;
    else if (nn < 20) ns[nn++] = i;
  }
  int iH = 0, iWd = 2, iWu = 3, iOps = 4, iWr = 5, iSl = 6, iRe = 7,
      iWk = 8, iWg = 9, iWv = 10, iMx = 11, iG = 12, iB = 13;
  if (nn >= 13) {
    iH  = ns[0];  iWd = ns[1];  iWu = ns[2];  iOps = ns[3]; iWr = ns[4];
    iSl = ns[5];  iRe = ns[6];  iWk = ns[7];  iWg = ns[8];  iWv = ns[9];
    iMx = ns[10]; iG  = ns[11]; iB  = ns[12];
  }
  const float* hidden   = (const float*)d_in[iH];
  const float* W_down   = (const float*)d_in[iWd];
  const float* W_up     = (const float*)d_in[iWu];
  const float* opsw     = (const float*)d_in[iOps];
  const float* W_router = (const float*)d_in[iWr];
  const float* slots    = (const float*)d_in[iSl];
  const float* W_read   = (const float*)d_in[iRe];
  const float* W_wk     = (const float*)d_in[iWk];
  const float* W_wg     = (const float*)d_in[iWg];
  const float* W_wv     = (const float*)d_in[iWv];
  const float* W_mix    = (const float*)d_in[iMx];
  const float* lng      = (const float*)d_in[iG];
  const float* lnb      = (const float*)d_in[iB];
  const float* wscale   = (lastsc >= 0) ? (const float*)d_in[lastsc] : (const float*)d_in[iG];
  const int has_wsc     = (lastsc >= 0) ? 1 : 0;

  char* ws = (char*)d_ws;
  float*  sums   = (float*)(ws + OFF_SUMS);
  float*  opsSc  = (float*)(ws + OFF_OPSSC);
  ushort* WdE    = (ushort*)(ws + OFF_WDE);
  ushort* WuE    = (ushort*)(ws + OFF_WUE);
  float*  WrT    = (float*)(ws + OFF_WRT);
  ushort* opsB   = (ushort*)(ws + OFF_OPSB);
  ushort* WmixA  = (ushort*)(ws + OFF_WMIXA);
  ushort* WwvB   = (ushort*)(ws + OFF_WWVB);
  float*  Mrs    = (float*)(ws + OFF_MRS);
  float*  Mws    = (float*)(ws + OFF_MWS);
  float*  SBw    = (float*)(ws + OFF_SB);
  float*  slotsF = (float*)(ws + OFF_SLOTS);
  float*  WwgF   = (float*)(ws + OFF_WWG);
  float*  gammaF = (float*)(ws + OFF_GAMMA);
  float*  betaF  = (float*)(ws + OFF_BETA);
  float*  wscF   = (float*)(ws + OFF_WSC);
  ushort* MrsE   = (ushort*)(ws + OFF_MRSE);
  ushort* MwsE   = (ushort*)(ws + OFF_MWSE);
  ushort* RF     = (ushort*)(ws + OFF_RF);

  float* X = (float*)d_out;

  k_absum_all<<<35, 1024, 0, stream>>>(W_down, W_router, W_up, opsw, sums);
  k_build<<<3266, 256, 0, stream>>>(W_down, W_up, W_router, opsw, W_read, W_wk, W_wg,
                                    W_wv, W_mix, slots, lng, lnb, wscale, has_wsc,
                                    sums, WdE, WuE, WrT, opsB, opsSc, WmixA, WwvB,
                                    Mrs, Mws, SBw, slotsF, WwgF, gammaF, betaF, wscF,
                                    MrsE, MwsE);
  k_down<<<256, 512, 0, stream>>>(hidden, WdE, X);
  k_pass2<<<256, 512, 0, stream>>>(X, RF, 0, WrT, opsB, opsSc, WmixA, MrsE, SBw,
                                   gammaF, betaF, WwvB, MwsE, slotsF, WwgF, wscF);
  k_pass2<<<256, 512, 0, stream>>>(X, RF, 1, WrT, opsB, opsSc, WmixA, MrsE, SBw,
                                   gammaF, betaF, WwvB, MwsE, slotsF, WwgF, wscF);
  k_up<<<2048, 256, 0, stream>>>(RF, WuE, hidden, X);
}